// Round 5
// baseline (644.443 us; speedup 1.0000x reference)
//
#include <hip/hip_runtime.h>

#define SS 128
#define RR 128
#define CC 128
#define RC (RR * CC)
#define LS 4            // s-planes per block (rotation)
#define EPSF 1e-14f

// Block = 256 threads = 8 rows x 32 float4-cols, iterating LS s-planes.
// s-diff: register rotation. r-diff: even rows via __shfl_down(32) (row pair
// lives in one wave), odd rows via global re-read (cache hit). c-diff: shfl.
// NO barriers in the hot loop -> loads pipeline freely across steps.
__global__ __launch_bounds__(256, 4) void scol_main(const float* __restrict__ L,
                                                    const float* __restrict__ U,
                                                    float4* __restrict__ part,
                                                    int sChunks, int rChunks) {
    const int SRC = SS * RC;

    int tid  = threadIdx.x;
    int c4   = tid & 31;
    int rblk = tid >> 5;
    bool odd = (rblk & 1);

    int g  = blockIdx.x;
    int sc = g % sChunks;
    int rc = (g / sChunks) % rChunks;
    int b  = g / (sChunks * rChunks);

    int r  = rc * 8 + rblk;
    int s0 = sc * LS;
    int c  = c4 << 2;

    bool  hc = (c4 < 31);
    float wc = hc ? 1.f : 0.f;
    bool  hr = (r < RR - 1);
    float wr_odd = hr ? 1.f : 0.f;        // only odd rows can be at r=127
    int   offr   = hr ? CC : 0;
    float wrv    = odd ? wr_odd : 1.f;    // even rows: partner always in-wave

    int pos    = (s0 * RR + r) * CC + c;
    int base_l = b * 3 * SRC;
    int base_u = b * 9 * SRC;

    // ---- prologue: u_cur = U(s0) ----
    float4 ucur[9];
#pragma unroll
    for (int ch = 0; ch < 9; ++ch)
        ucur[ch] = *(const float4*)(U + base_u + ch * SRC + pos);

    float a_co = 0.f, a_ds = 0.f, a_dr = 0.f, a_dc = 0.f;

#pragma unroll
    for (int i = 0; i < LS; ++i) {
        int s = s0 + i;
        bool  hs  = (s < SS - 1);
        float wsf = hs ? 1.f : 0.f;
        int offn  = hs ? RC : 0;

        // ---- batched load phase ----
        float4 l0 = *(const float4*)(L + base_l + pos);
        float4 l1 = *(const float4*)(L + base_l + SRC + pos);
        float4 l2 = *(const float4*)(L + base_l + 2 * SRC + pos);

        float4 unx[9];
#pragma unroll
        for (int ch = 0; ch < 9; ++ch)
            unx[ch] = *(const float4*)(U + base_u + ch * SRC + pos + offn);

        float4 urg[9];
        if (odd) {
#pragma unroll
            for (int ch = 0; ch < 9; ++ch)
                urg[ch] = *(const float4*)(U + base_u + ch * SRC + pos + offr);
        }

        // ---- argmax over L channels ----
        float L0[4] = {l0.x, l0.y, l0.z, l0.w};
        float L1[4] = {l1.x, l1.y, l1.z, l1.w};
        float L2[4] = {l2.x, l2.y, l2.z, l2.w};
        int idx[4];
#pragma unroll
        for (int j = 0; j < 4; ++j) {
            int id = 0;
            float best = L0[j];
            if (L1[j] > best) { best = L1[j]; id = 1; }
            if (L2[j] > best) { best = L2[j]; id = 2; }
            idx[j] = id;
        }

        float am[3][4];
#pragma unroll
        for (int gi = 0; gi < 3; ++gi)
#pragma unroll
            for (int j = 0; j < 4; ++j) am[gi][j] = 0.f;

        float t_dcb = 0.f, t_dr = 0.f, t_ds = 0.f;

#pragma unroll
        for (int ch = 0; ch < 9; ++ch) {
            float4 uu = ucur[ch];
            float uuv[4] = {uu.x, uu.y, uu.z, uu.w};
            int gi = ch / 3, m = ch % 3;
#pragma unroll
            for (int j = 0; j < 4; ++j)
                if (idx[j] == m) am[gi][j] = fabsf(uuv[j]);

            float d;
            d = uu.y - uu.x; a_dc += d * d;
            d = uu.z - uu.y; a_dc += d * d;
            d = uu.w - uu.z; a_dc += d * d;
            float un1 = __shfl_down(uu.x, 1);
            d = un1 - uu.w; t_dcb += d * d;

            // r-neighbor: even rows from upper half-wave, odd rows from global
            float4 Rsh;
            Rsh.x = __shfl_down(uu.x, 32);
            Rsh.y = __shfl_down(uu.y, 32);
            Rsh.z = __shfl_down(uu.z, 32);
            Rsh.w = __shfl_down(uu.w, 32);
            float4 R4 = odd ? urg[ch] : Rsh;
            d = R4.x - uu.x; t_dr += d * d;
            d = R4.y - uu.y; t_dr += d * d;
            d = R4.z - uu.z; t_dr += d * d;
            d = R4.w - uu.w; t_dr += d * d;

            float4 S4 = unx[ch];
            d = S4.x - uu.x; t_ds += d * d;
            d = S4.y - uu.y; t_ds += d * d;
            d = S4.z - uu.z; t_ds += d * d;
            d = S4.w - uu.w; t_ds += d * d;

            ucur[ch] = S4;   // rotate
        }
        a_dc += wc * t_dcb;
        a_dr += wrv * t_dr;
        a_ds += wsf * t_ds;

#pragma unroll
        for (int j = 0; j < 4; ++j) {
            float e1 = am[0][j], e2 = am[1][j], e3 = am[2][j];
            float den = e1 * e1 + e2 * e2 + e3 * e3;
            den = fmaxf(den, EPSF);
            float num = 0.5f * ((e1 - e2) * (e1 - e2) + (e2 - e3) * (e2 - e3) +
                                (e3 - e1) * (e3 - e1));
            a_co += sqrtf(num / den);
        }

        pos += RC;
    }

    // ---- wave reduce (64 lanes) ----
#pragma unroll
    for (int off = 32; off > 0; off >>= 1) {
        a_co += __shfl_down(a_co, off);
        a_ds += __shfl_down(a_ds, off);
        a_dr += __shfl_down(a_dr, off);
        a_dc += __shfl_down(a_dc, off);
    }

    __shared__ float s_co[4], s_ds[4], s_dr[4], s_dc[4];
    int wid  = threadIdx.x >> 6;
    int lane = threadIdx.x & 63;
    if (lane == 0) {
        s_co[wid] = a_co; s_ds[wid] = a_ds;
        s_dr[wid] = a_dr; s_dc[wid] = a_dc;
    }
    __syncthreads();
    if (threadIdx.x == 0) {
        float t_co = 0.f, t_s = 0.f, t_r = 0.f, t_c = 0.f;
        for (int w = 0; w < 4; ++w) {
            t_co += s_co[w]; t_s += s_ds[w];
            t_r += s_dr[w]; t_c += s_dc[w];
        }
        part[blockIdx.x] = make_float4(t_co, t_s, t_r, t_c);
    }
}

// Single block: reduce nblk float4 partials in double, emit the scalar.
__global__ __launch_bounds__(256) void scol_final(const float4* __restrict__ part,
                                                  float* __restrict__ out,
                                                  int nblk, int B) {
    double d_co = 0., d_ds = 0., d_dr = 0., d_dc = 0.;
    for (int i = threadIdx.x; i < nblk; i += blockDim.x) {
        float4 p = part[i];
        d_co += (double)p.x; d_ds += (double)p.y;
        d_dr += (double)p.z; d_dc += (double)p.w;
    }
#pragma unroll
    for (int off = 32; off > 0; off >>= 1) {
        d_co += __shfl_down(d_co, off);
        d_ds += __shfl_down(d_ds, off);
        d_dr += __shfl_down(d_dr, off);
        d_dc += __shfl_down(d_dc, off);
    }
    __shared__ double sh[4][4];
    int wid  = threadIdx.x >> 6;
    int lane = threadIdx.x & 63;
    if (lane == 0) {
        sh[wid][0] = d_co; sh[wid][1] = d_ds;
        sh[wid][2] = d_dr; sh[wid][3] = d_dc;
    }
    __syncthreads();
    if (threadIdx.x == 0) {
        double t_co = 0., t_ds = 0., t_dr = 0., t_dc = 0.;
        for (int w = 0; w < 4; ++w) {
            t_co += sh[w][0]; t_ds += sh[w][1];
            t_dr += sh[w][2]; t_dc += sh[w][3];
        }
        double nvox = (double)B * SS * RR * CC;
        double nds  = (double)B * (SS - 1) * RR * CC;
        double ndr  = (double)B * SS * (RR - 1) * CC;
        double ndc  = (double)B * SS * RR * (CC - 1);
        out[0] = (float)(0.5 * (t_co / nvox + t_ds / nds + t_dr / ndr + t_dc / ndc));
    }
}

extern "C" void kernel_launch(void* const* d_in, const int* in_sizes, int n_in,
                              void* d_out, int out_size, void* d_ws, size_t ws_size,
                              hipStream_t stream) {
    const float* L = (const float*)d_in[0];
    const float* U = (const float*)d_in[1];
    float* out = (float*)d_out;

    int B = in_sizes[1] / (9 * SS * RR * CC);
    int sChunks = SS / LS;        // 32
    int rChunks = RR / 8;         // 16
    int blocks  = B * sChunks * rChunks;   // 1024 for B=2

    float4* part = (float4*)d_ws;

    hipLaunchKernelGGL(scol_main, dim3(blocks), dim3(256), 0, stream,
                       L, U, part, sChunks, rChunks);
    hipLaunchKernelGGL(scol_final, dim3(1), dim3(256), 0, stream,
                       part, out, blocks, B);
}

// Round 6
// 261.826 us; speedup vs baseline: 2.4613x; 2.4613x over previous
//
#include <hip/hip_runtime.h>
#include <stdint.h>

#define SS 128
#define RR 128
#define CC 128
#define RC (RR * CC)
#define SRC (SS * RC)
#define LS 8            // s-planes per block
#define EPSF 1e-14f

// Per-buffer LDS layout (floats):
//   [0 .. 4607]    slab: ch*512 + row*128 + c   (9 ch x 4 rows x 128 cols)
//   [4608 .. 5759] bnd:  ch*128 + c             (9 ch x row r0+4, clamped)
#define SLAB_F 4608
#define BND_F 1152
#define BUF_F (SLAB_F + BND_F)   // 5760 floats = 23040 B per buffer

__device__ __forceinline__ void dma16(const float* g, float* l) {
    __builtin_amdgcn_global_load_lds(
        (const __attribute__((address_space(1))) uint32_t*)g,
        (__attribute__((address_space(3))) uint32_t*)l,
        16, 0, 0);
}

// Block = 128 threads = 4 rows x 32 float4-cols, sweeping LS s-planes.
// Plane s+1 DMA'd to LDS (global_load_lds, no VGPR cost) while computing
// plane s from LDS. s-diff via uprev register rotation. One barrier/plane.
__global__ __launch_bounds__(128, 4) void scol_main(const float* __restrict__ L,
                                                    const float* __restrict__ U,
                                                    float4* __restrict__ part) {
    __shared__ float lds[2][BUF_F];
    __shared__ float sred[2][4];

    const int tid = threadIdx.x;
    const int c4  = tid & 31;
    const int row = tid >> 5;          // 0..3

    int g   = blockIdx.x;
    int rcI = g & 31;                  // 32 r-chunks
    int scI = (g >> 5) & 15;           // 16 s-chunks
    int b   = g >> 9;

    int r0 = rcI << 2;
    int s0 = scI << 3;
    int r  = r0 + row;
    int c  = c4 << 2;

    const float* Ub = U + (size_t)b * 9 * SRC;
    const float* Lb = L + (size_t)b * 3 * SRC;

    float wc = (c4 < 31) ? 1.f : 0.f;
    float wr = (r < RR - 1) ? 1.f : 0.f;
    int rowb = (r0 + 4 < RR) ? (r0 + 4) : (RR - 1);   // bnd source row (clamped)

    // ---- prologue: uprev = own float4 of plane s0-1 (clamped; s==0 weighted 0) ----
    float4 uprev[9];
    {
        int sprev = (s0 > 0) ? (s0 - 1) : 0;
        const float* p = Ub + sprev * RC + r * CC + c;
#pragma unroll
        for (int ch = 0; ch < 9; ++ch)
            uprev[ch] = *(const float4*)(p + ch * SRC);
    }

    // ---- prologue DMA: plane s0 -> buf 0 ----
    {
        float* dst = &lds[0][0];
        const float* srcP = Ub + s0 * RC + r0 * CC;   // rows r0..r0+3 contiguous
#pragma unroll
        for (int ch = 0; ch < 9; ++ch)
            dma16(srcP + ch * SRC + tid * 4, dst + ch * 512 + tid * 4);
        const float* srcB = Ub + s0 * RC + rowb * CC;
        int chp = tid >> 5, col = c4 << 2;
        dma16(srcB + chp * SRC + col,       dst + SLAB_F + tid * 4);
        dma16(srcB + (chp + 4) * SRC + col, dst + SLAB_F + 512 + tid * 4);
        if (tid < 32)
            dma16(srcB + 8 * SRC + col,     dst + SLAB_F + 1024 + tid * 4);
    }

    float a_co = 0.f, a_ds = 0.f, a_dr = 0.f, a_dc = 0.f;

    for (int i = 0; i < LS; ++i) {
        int s  = s0 + i;
        int bb = i & 1;

        // Barrier: (a) waits own-wave vmcnt -> previous DMA into lds[bb] done
        // for every wave; (b) all waves finished reading lds[bb^1] last iter,
        // so it is safe to DMA-overwrite it below.
        __syncthreads();

        if (i < LS - 1) {
            float* dst = &lds[bb ^ 1][0];
            int sp = s + 1;
            const float* srcP = Ub + sp * RC + r0 * CC;
#pragma unroll
            for (int ch = 0; ch < 9; ++ch)
                dma16(srcP + ch * SRC + tid * 4, dst + ch * 512 + tid * 4);
            const float* srcB = Ub + sp * RC + rowb * CC;
            int chp = tid >> 5, col = c4 << 2;
            dma16(srcB + chp * SRC + col,       dst + SLAB_F + tid * 4);
            dma16(srcB + (chp + 4) * SRC + col, dst + SLAB_F + 512 + tid * 4);
            if (tid < 32)
                dma16(srcB + 8 * SRC + col,     dst + SLAB_F + 1024 + tid * 4);
        }

        // L loads (global; consumed only at argmax below -> latency covered
        // by the LDS diff work in between)
        const float* lp = Lb + s * RC + r * CC + c;
        float4 l0 = *(const float4*)(lp);
        float4 l1 = *(const float4*)(lp + SRC);
        float4 l2 = *(const float4*)(lp + 2 * SRC);

        const float* buf  = &lds[bb][0];
        const float* ownB = buf + row * 128 + c;                       // + ch*512
        const float* rnB  = (row < 3) ? (buf + (row + 1) * 128 + c)
                                      : (buf + SLAB_F + c);
        int rnStride = (row < 3) ? 512 : 128;

        float wsd = (s > 0) ? 1.f : 0.f;

        float t_ds = 0.f, t_dr = 0.f, t_dcb = 0.f;
#pragma unroll
        for (int ch = 0; ch < 9; ++ch) {
            float4 own = *(const float4*)(ownB + ch * 512);
            float4 rn  = *(const float4*)(rnB + ch * rnStride);
            float  cn  = *(ownB + ch * 512 + 4);   // elem c+4 (edge: garbage, wc=0)
            float d;
            d = own.y - own.x; a_dc += d * d;
            d = own.z - own.y; a_dc += d * d;
            d = own.w - own.z; a_dc += d * d;
            d = cn    - own.w; t_dcb += d * d;
            d = rn.x - own.x; t_dr += d * d;
            d = rn.y - own.y; t_dr += d * d;
            d = rn.z - own.z; t_dr += d * d;
            d = rn.w - own.w; t_dr += d * d;
            float4 up = uprev[ch];
            d = own.x - up.x; t_ds += d * d;
            d = own.y - up.y; t_ds += d * d;
            d = own.z - up.z; t_ds += d * d;
            d = own.w - up.w; t_ds += d * d;
            uprev[ch] = own;   // rotate for next plane's s-diff
        }
        a_dc += wc * t_dcb;
        a_dr += wr * t_dr;
        a_ds += wsd * t_ds;

        // ---- argmax + CO: selected |u| re-read from LDS (12 x ds_read_b32) ----
        float Lv0[4] = {l0.x, l0.y, l0.z, l0.w};
        float Lv1[4] = {l1.x, l1.y, l1.z, l1.w};
        float Lv2[4] = {l2.x, l2.y, l2.z, l2.w};
#pragma unroll
        for (int j = 0; j < 4; ++j) {
            int id = 0;
            float best = Lv0[j];
            if (Lv1[j] > best) { best = Lv1[j]; id = 1; }
            if (Lv2[j] > best) { best = Lv2[j]; id = 2; }
            float e1 = fabsf(*(ownB + (0 + id) * 512 + j));
            float e2 = fabsf(*(ownB + (3 + id) * 512 + j));
            float e3 = fabsf(*(ownB + (6 + id) * 512 + j));
            float den = e1 * e1 + e2 * e2 + e3 * e3;
            den = fmaxf(den, EPSF);
            float num = 0.5f * ((e1 - e2) * (e1 - e2) + (e2 - e3) * (e2 - e3) +
                                (e3 - e1) * (e3 - e1));
            a_co += sqrtf(num / den);
        }
    }

    // ---- wave reduce (64 lanes) + block combine (2 waves) ----
#pragma unroll
    for (int off = 32; off > 0; off >>= 1) {
        a_co += __shfl_down(a_co, off);
        a_ds += __shfl_down(a_ds, off);
        a_dr += __shfl_down(a_dr, off);
        a_dc += __shfl_down(a_dc, off);
    }
    int wid = tid >> 6, lane = tid & 63;
    if (lane == 0) {
        sred[wid][0] = a_co; sred[wid][1] = a_ds;
        sred[wid][2] = a_dr; sred[wid][3] = a_dc;
    }
    __syncthreads();
    if (tid == 0) {
        part[blockIdx.x] = make_float4(sred[0][0] + sred[1][0],
                                       sred[0][1] + sred[1][1],
                                       sred[0][2] + sred[1][2],
                                       sred[0][3] + sred[1][3]);
    }
}

// Single block: reduce nblk float4 partials in double, emit the scalar.
__global__ __launch_bounds__(256) void scol_final(const float4* __restrict__ part,
                                                  float* __restrict__ out,
                                                  int nblk, int B) {
    double d_co = 0., d_ds = 0., d_dr = 0., d_dc = 0.;
    for (int i = threadIdx.x; i < nblk; i += blockDim.x) {
        float4 p = part[i];
        d_co += (double)p.x; d_ds += (double)p.y;
        d_dr += (double)p.z; d_dc += (double)p.w;
    }
#pragma unroll
    for (int off = 32; off > 0; off >>= 1) {
        d_co += __shfl_down(d_co, off);
        d_ds += __shfl_down(d_ds, off);
        d_dr += __shfl_down(d_dr, off);
        d_dc += __shfl_down(d_dc, off);
    }
    __shared__ double sh[4][4];
    int wid = threadIdx.x >> 6, lane = threadIdx.x & 63;
    if (lane == 0) {
        sh[wid][0] = d_co; sh[wid][1] = d_ds;
        sh[wid][2] = d_dr; sh[wid][3] = d_dc;
    }
    __syncthreads();
    if (threadIdx.x == 0) {
        double t_co = 0., t_ds = 0., t_dr = 0., t_dc = 0.;
        for (int w = 0; w < 4; ++w) {
            t_co += sh[w][0]; t_ds += sh[w][1];
            t_dr += sh[w][2]; t_dc += sh[w][3];
        }
        double nvox = (double)B * SS * RR * CC;
        double nds  = (double)B * (SS - 1) * RR * CC;
        double ndr  = (double)B * SS * (RR - 1) * CC;
        double ndc  = (double)B * SS * RR * (CC - 1);
        out[0] = (float)(0.5 * (t_co / nvox + t_ds / nds + t_dr / ndr + t_dc / ndc));
    }
}

extern "C" void kernel_launch(void* const* d_in, const int* in_sizes, int n_in,
                              void* d_out, int out_size, void* d_ws, size_t ws_size,
                              hipStream_t stream) {
    const float* L = (const float*)d_in[0];
    const float* U = (const float*)d_in[1];
    float* out = (float*)d_out;

    int B = in_sizes[1] / (9 * SS * RR * CC);
    int blocks = B * 32 * 16;   // rchunks(32) x schunks(16) per batch = 1024 for B=2

    float4* part = (float4*)d_ws;

    hipLaunchKernelGGL(scol_main, dim3(blocks), dim3(128), 0, stream,
                       L, U, part);
    hipLaunchKernelGGL(scol_final, dim3(1), dim3(256), 0, stream,
                       part, out, blocks, B);
}

// Round 7
// 249.757 us; speedup vs baseline: 2.5803x; 1.0483x over previous
//
#include <hip/hip_runtime.h>

#define SS 128
#define RR 128
#define CC 128
#define RC (RR * CC)
#define VOL (SS * RC)        // per-channel volume (same for L and U)
#define EPSF 1e-14f

// Block = 256 threads = 4 waves over the SAME 64 voxel-vectors (2 full c-rows).
// Waves 0-2: U channel-group g = {3g,3g+1,3g+2}: 9 coalesced b128 loads
//   (own + s-neighbor + r-neighbor), diffs, then e_g selection.
// Wave 3: 3 L loads -> packed argmax -> LDS; then CO from exchanged e_g.
// Each wave: ONE vmcnt round (~9 loads live = 36 VGPR).
__global__ __launch_bounds__(256, 8) void scol_main(const float* __restrict__ L,
                                                    const float* __restrict__ U,
                                                    float4* __restrict__ part,
                                                    int nblocks) {
    __shared__ int    lidx[64];
    __shared__ float4 lde[3][64];
    __shared__ float  sred[4][4];

    const int tid  = threadIdx.x;
    const int wid  = tid >> 6;
    const int lane = tid & 63;
    const int half = lane >> 5;
    const int c4   = lane & 31;

    // XCD swizzle: consecutive HW blocks round-robin XCDs (%8); remap so each
    // XCD works a contiguous (b,s) slab -> neighbor re-reads hit its own L2.
    int id = blockIdx.x;
    if ((nblocks & 7) == 0) {
        int per = nblocks >> 3;
        id = (blockIdx.x & 7) * per + (blockIdx.x >> 3);
    }

    int rp = id & 63;                  // row-pair
    int s  = (id >> 6) & (SS - 1);
    int b  = id / (64 * SS);

    int r = rp * 2 + half;
    int c = c4 << 2;

    float wc = (c4 < 31) ? 1.f : 0.f;
    float wr = (r < RR - 1) ? 1.f : 0.f;
    float ws = (s < SS - 1) ? 1.f : 0.f;
    int offr = (r < RR - 1) ? CC : 0;
    int offs = (s < SS - 1) ? RC : 0;

    size_t posPlane = (size_t)s * RC + (size_t)r * CC + c;

    float a_co = 0.f, a_ds = 0.f, a_dr = 0.f, a_dc = 0.f;

    float4 own[3];   // kept live into the e-selection phase (waves 0-2)

    // ---------------- phase 1 ----------------
    if (wid < 3) {
        const float* p0 = U + ((size_t)(b * 9 + 3 * wid)) * VOL + posPlane;
        float4 sn[3], rn[3];
#pragma unroll
        for (int k = 0; k < 3; ++k) {
            const float* p = p0 + (size_t)k * VOL;
            own[k] = *(const float4*)(p);
            sn[k]  = *(const float4*)(p + offs);
            rn[k]  = *(const float4*)(p + offr);
        }
        float t_dcb = 0.f, t_dr = 0.f, t_ds = 0.f;
#pragma unroll
        for (int k = 0; k < 3; ++k) {
            float4 o = own[k];
            float d;
            d = o.y - o.x; a_dc += d * d;
            d = o.z - o.y; a_dc += d * d;
            d = o.w - o.z; a_dc += d * d;
            float cn = __shfl_down(o.x, 1);     // lane31/63 garbage -> wc=0
            d = cn - o.w; t_dcb += d * d;
            float4 R4 = rn[k];
            d = R4.x - o.x; t_dr += d * d;
            d = R4.y - o.y; t_dr += d * d;
            d = R4.z - o.z; t_dr += d * d;
            d = R4.w - o.w; t_dr += d * d;
            float4 S4 = sn[k];
            d = S4.x - o.x; t_ds += d * d;
            d = S4.y - o.y; t_ds += d * d;
            d = S4.z - o.z; t_ds += d * d;
            d = S4.w - o.w; t_ds += d * d;
        }
        a_dc += wc * t_dcb;
        a_dr  = wr * t_dr;
        a_ds  = ws * t_ds;
    } else {
        const float* lp = L + ((size_t)(b * 3)) * VOL + posPlane;
        float4 l0 = *(const float4*)(lp);
        float4 l1 = *(const float4*)(lp + VOL);
        float4 l2 = *(const float4*)(lp + 2 * VOL);
        float A0[4] = {l0.x, l0.y, l0.z, l0.w};
        float A1[4] = {l1.x, l1.y, l1.z, l1.w};
        float A2[4] = {l2.x, l2.y, l2.z, l2.w};
        int pk = 0;
#pragma unroll
        for (int j = 0; j < 4; ++j) {
            int idj = 0;
            float best = A0[j];
            if (A1[j] > best) { best = A1[j]; idj = 1; }
            if (A2[j] > best) { idj = 2; }
            pk |= idj << (2 * j);
        }
        lidx[lane] = pk;
    }

    __syncthreads();   // idx ready; U loads already consumed

    // ---------------- phase 2: e_g selection ----------------
    if (wid < 3) {
        int pk = lidx[lane];
        float e[4];
        float O0[4] = {own[0].x, own[0].y, own[0].z, own[0].w};
        float O1[4] = {own[1].x, own[1].y, own[1].z, own[1].w};
        float O2[4] = {own[2].x, own[2].y, own[2].z, own[2].w};
#pragma unroll
        for (int j = 0; j < 4; ++j) {
            int m = (pk >> (2 * j)) & 3;
            float v = (m == 0) ? O0[j] : (m == 1) ? O1[j] : O2[j];
            e[j] = fabsf(v);
        }
        lde[wid][lane] = make_float4(e[0], e[1], e[2], e[3]);
    }

    __syncthreads();   // e ready

    // ---------------- phase 3: CO (wave 3) ----------------
    if (wid == 3) {
        float4 e0 = lde[0][lane];
        float4 e1 = lde[1][lane];
        float4 e2 = lde[2][lane];
        float E0[4] = {e0.x, e0.y, e0.z, e0.w};
        float E1[4] = {e1.x, e1.y, e1.z, e1.w};
        float E2[4] = {e2.x, e2.y, e2.z, e2.w};
#pragma unroll
        for (int j = 0; j < 4; ++j) {
            float x = E0[j], y = E1[j], z = E2[j];
            float den = x * x + y * y + z * z;
            den = fmaxf(den, EPSF);
            float num = 0.5f * ((x - y) * (x - y) + (y - z) * (y - z) +
                                (z - x) * (z - x));
            a_co += sqrtf(num / den);
        }
    }

    // ---------------- reduce ----------------
#pragma unroll
    for (int off = 32; off > 0; off >>= 1) {
        a_co += __shfl_down(a_co, off);
        a_ds += __shfl_down(a_ds, off);
        a_dr += __shfl_down(a_dr, off);
        a_dc += __shfl_down(a_dc, off);
    }
    if (lane == 0) {
        sred[wid][0] = a_co; sred[wid][1] = a_ds;
        sred[wid][2] = a_dr; sred[wid][3] = a_dc;
    }
    __syncthreads();
    if (tid == 0) {
        float t_co = 0.f, t_s = 0.f, t_r = 0.f, t_c = 0.f;
#pragma unroll
        for (int w = 0; w < 4; ++w) {
            t_co += sred[w][0]; t_s += sred[w][1];
            t_r += sred[w][2]; t_c += sred[w][3];
        }
        part[blockIdx.x] = make_float4(t_co, t_s, t_r, t_c);
    }
}

// 1024 threads, single block: reduce nblk float4 partials in double.
__global__ __launch_bounds__(1024) void scol_final(const float4* __restrict__ part,
                                                   float* __restrict__ out,
                                                   int nblk, int B) {
    double d_co = 0., d_ds = 0., d_dr = 0., d_dc = 0.;
    for (int i = threadIdx.x; i < nblk; i += blockDim.x) {
        float4 p = part[i];
        d_co += (double)p.x; d_ds += (double)p.y;
        d_dr += (double)p.z; d_dc += (double)p.w;
    }
#pragma unroll
    for (int off = 32; off > 0; off >>= 1) {
        d_co += __shfl_down(d_co, off);
        d_ds += __shfl_down(d_ds, off);
        d_dr += __shfl_down(d_dr, off);
        d_dc += __shfl_down(d_dc, off);
    }
    __shared__ double sh[16][4];
    int wid = threadIdx.x >> 6, lane = threadIdx.x & 63;
    if (lane == 0) {
        sh[wid][0] = d_co; sh[wid][1] = d_ds;
        sh[wid][2] = d_dr; sh[wid][3] = d_dc;
    }
    __syncthreads();
    if (threadIdx.x == 0) {
        double t_co = 0., t_ds = 0., t_dr = 0., t_dc = 0.;
        int nw = blockDim.x >> 6;
        for (int w = 0; w < nw; ++w) {
            t_co += sh[w][0]; t_ds += sh[w][1];
            t_dr += sh[w][2]; t_dc += sh[w][3];
        }
        double nvox = (double)B * SS * RR * CC;
        double nds  = (double)B * (SS - 1) * RR * CC;
        double ndr  = (double)B * SS * (RR - 1) * CC;
        double ndc  = (double)B * SS * RR * (CC - 1);
        out[0] = (float)(0.5 * (t_co / nvox + t_ds / nds + t_dr / ndr + t_dc / ndc));
    }
}

extern "C" void kernel_launch(void* const* d_in, const int* in_sizes, int n_in,
                              void* d_out, int out_size, void* d_ws, size_t ws_size,
                              hipStream_t stream) {
    const float* L = (const float*)d_in[0];
    const float* U = (const float*)d_in[1];
    float* out = (float*)d_out;

    int B = in_sizes[1] / (9 * SS * RR * CC);
    int nblocks = B * SS * (RR / 2);    // 16384 for B=2

    float4* part = (float4*)d_ws;

    hipLaunchKernelGGL(scol_main, dim3(nblocks), dim3(256), 0, stream,
                       L, U, part, nblocks);
    hipLaunchKernelGGL(scol_final, dim3(1), dim3(1024), 0, stream,
                       part, out, nblocks, B);
}